// Round 1
// baseline (100.552 us; speedup 1.0000x reference)
//
#include <hip/hip_runtime.h>
#include <hip/hip_bf16.h>

typedef unsigned short u16;
typedef __attribute__((ext_vector_type(8))) short bhalf8;
typedef __attribute__((ext_vector_type(4))) float fx4;

struct __align__(8) US4 { u16 v[4]; };

__device__ __forceinline__ u16 f2bf(float x) {
  union { float f; unsigned int u; } c; c.f = x;
  unsigned int r = c.u + 0x7FFFu + ((c.u >> 16) & 1u);
  return (u16)(r >> 16);
}

__device__ __forceinline__ void gload16(const void* g, void* l) {
  __builtin_amdgcn_global_load_lds((const __attribute__((address_space(1))) void*)g,
                                   (__attribute__((address_space(3))) void*)l,
                                   16, 0, 0);
}

#define MFMA16(a, b, c) __builtin_amdgcn_mfma_f32_16x16x32_bf16((a), (b), (c), 0, 0, 0)

// ---------------- input conversion ----------------
__global__ void k_conv(const float* __restrict__ in, u16* __restrict__ out, int n4) {
  int i = blockIdx.x * 256 + threadIdx.x;
  if (i < n4) {
    float4 v = ((const float4*)in)[i];
    US4 o;
    o.v[0] = f2bf(v.x); o.v[1] = f2bf(v.y); o.v[2] = f2bf(v.z); o.v[3] = f2bf(v.w);
    ((US4*)out)[i] = o;
  }
}

// transpose [R][C] f32 -> [C][R] bf16, 64x64 tiles
__global__ void k_transpose(const float* __restrict__ in, u16* __restrict__ out,
                            int R, int C, int rtiles) {
  __shared__ float tile[64][65];
  const int bx = blockIdx.x;
  const int rt = bx % rtiles, ct = bx / rtiles;
  const int r0 = rt * 64, c0 = ct * 64;
  const int t = threadIdx.x;
  #pragma unroll
  for (int i = 0; i < 16; ++i) {
    int e = i * 256 + t;
    int rr = e >> 6, cc = e & 63;
    tile[rr][cc] = in[(r0 + rr) * C + c0 + cc];
  }
  __syncthreads();
  #pragma unroll
  for (int i = 0; i < 16; ++i) {
    int e = i * 256 + t;
    int rr = e >> 6, cc = e & 63;
    out[(c0 + rr) * R + r0 + cc] = f2bf(tile[cc][rr]);
  }
}

// ---------------- shared 128x128 GEMM mainloop (K=512, both operand row strides = 1024B) ----------------
__device__ __forceinline__ void gemm_core(const char* Ab, const char* Bb,
                                          char* As, char* Bs, fx4 acc[4][4]) {
  const int t = threadIdx.x;
  const int w = t >> 6, l = t & 63;
  const int wm = w >> 1, wn = w & 1;
  #pragma unroll 1
  for (int kt = 0; kt < 8; ++kt) {
    __syncthreads();
    const int kb = kt * 128;
    #pragma unroll
    for (int j = 0; j < 4; ++j) {
      int off = ((j * 4 + w) * 64 + l) * 16;     // byte offset in 16KB tile
      int row = off >> 7;
      int colb = off & 127;
      int scol = colb ^ ((row & 7) << 4);        // pre-swizzled global source
      gload16(Ab + row * 1024 + kb + scol, As + off);
      gload16(Bb + row * 1024 + kb + scol, Bs + off);
    }
    asm volatile("s_waitcnt vmcnt(0)" ::: "memory");
    __syncthreads();
    #pragma unroll
    for (int ks = 0; ks < 2; ++ks) {
      bhalf8 af[4], bfv[4];
      const int kbyte = ks * 64 + ((l >> 4) * 16);
      #pragma unroll
      for (int f = 0; f < 4; ++f) {
        int ra = wm * 64 + f * 16 + (l & 15);
        af[f] = *(const bhalf8*)(As + ra * 128 + (kbyte ^ ((ra & 7) << 4)));
        int rb = wn * 64 + f * 16 + (l & 15);
        bfv[f] = *(const bhalf8*)(Bs + rb * 128 + (kbyte ^ ((rb & 7) << 4)));
      }
      #pragma unroll
      for (int fm = 0; fm < 4; ++fm)
        #pragma unroll
        for (int fn = 0; fn < 4; ++fn)
          acc[fm][fn] = MFMA16(af[fm], bfv[fn], acc[fm][fn]);
    }
  }
}

// ---------------- K1: qkv GEMM + fused q-softmax / k-exp-transpose / v-transpose ----------------
__global__ __launch_bounds__(256, 2)
void k_qkv_gemm(const char* __restrict__ xb, const char* __restrict__ wqT,
                u16* __restrict__ qhat, u16* __restrict__ kT, u16* __restrict__ vT) {
  __shared__ __align__(16) char lds[32768];
  const int bx = blockIdx.x;
  const int tM = bx & 127, tN = bx >> 7;  // 128 M-tiles, 12 N-tiles
  fx4 acc[4][4];
  const fx4 z4 = {0.f, 0.f, 0.f, 0.f};
  #pragma unroll
  for (int i = 0; i < 4; ++i)
    #pragma unroll
    for (int j = 0; j < 4; ++j) acc[i][j] = z4;

  gemm_core(xb + tM * 131072, wqT + tN * 131072, lds, lds + 16384, acc);

  const int t = threadIdx.x, w = t >> 6, l = t & 63;
  const int wm = w >> 1, wn = w & 1;
  const int m0 = tM * 128 + wm * 64;
  const int c0 = tN * 128 + wn * 64;

  if (tN < 4) {
    // q: softmax over the 64 head-dim cols (exactly this wave's col span)
    #pragma unroll
    for (int fm = 0; fm < 4; ++fm) {
      #pragma unroll
      for (int fn = 0; fn < 4; ++fn)
        #pragma unroll
        for (int r = 0; r < 4; ++r)
          acc[fm][fn][r] = __expf(acc[fm][fn][r]);
      fx4 s = acc[fm][0] + acc[fm][1] + acc[fm][2] + acc[fm][3];
      fx4 inv;
      #pragma unroll
      for (int r = 0; r < 4; ++r) {
        float sv = s[r];
        sv += __shfl_xor(sv, 1, 64);
        sv += __shfl_xor(sv, 2, 64);
        sv += __shfl_xor(sv, 4, 64);
        sv += __shfl_xor(sv, 8, 64);
        inv[r] = 1.0f / sv;
      }
      #pragma unroll
      for (int fn = 0; fn < 4; ++fn)
        #pragma unroll
        for (int r = 0; r < 4; ++r) {
          int m = m0 + fm * 16 + ((l >> 4) * 4) + r;
          int c = c0 + fn * 16 + (l & 15);
          qhat[m * 512 + c] = f2bf(acc[fm][fn][r] * inv[r]);
        }
    }
  } else {
    const bool isK = (tN < 8);
    const int b = m0 >> 12;
    const int nb = m0 & 4095;
    const int hd0 = c0 - (isK ? 512 : 1024);
    u16* dst = isK ? kT : vT;
    #pragma unroll
    for (int fm = 0; fm < 4; ++fm)
      #pragma unroll
      for (int fn = 0; fn < 4; ++fn) {
        int hd = hd0 + fn * 16 + (l & 15);
        int n = nb + fm * 16 + ((l >> 4) * 4);
        US4 p;
        #pragma unroll
        for (int r = 0; r < 4; ++r) {
          float v = acc[fm][fn][r];
          if (isK) {
            float tt = v > 0.f ? v + 1.f : __expf(v);  // elu(v)+1
            v = __expf(tt);                            // softmax numerator (no max-sub needed)
          }
          p.v[r] = f2bf(v);
        }
        *(US4*)(dst + ((b * 512 + hd) << 12) + n) = p;
      }
  }
}

// ---------------- K3: context partials  ctx_raw[d][e] = sum_n kT[d][n]*vT[e][n]; Z via ones-MFMA ----------------
__global__ __launch_bounds__(64)
void k_ctx(const u16* __restrict__ kT, const u16* __restrict__ vT,
           float* __restrict__ ctx_part, float* __restrict__ z_part) {
  const int bx = blockIdx.x;          // 512 = 32 (b,h) * 16 n-chunks
  const int bh = bx >> 4, nc = bx & 15;
  const int l = threadIdx.x;
  fx4 acc[4][4], az[4];
  const fx4 z4 = {0.f, 0.f, 0.f, 0.f};
  #pragma unroll
  for (int i = 0; i < 4; ++i) {
    az[i] = z4;
    #pragma unroll
    for (int j = 0; j < 4; ++j) acc[i][j] = z4;
  }
  bhalf8 ones;
  #pragma unroll
  for (int i = 0; i < 8; ++i) ones[i] = (short)0x3F80;  // bf16 1.0

  const int n0 = nc * 256 + ((l >> 4) * 8);
  #pragma unroll 1
  for (int it = 0; it < 8; ++it) {
    const int nb = n0 + it * 32;
    bhalf8 a[4], bv[4];
    #pragma unroll
    for (int f = 0; f < 4; ++f) {
      a[f]  = *(const bhalf8*)(kT + (bh * 64 + f * 16 + (l & 15)) * 4096 + nb);
      bv[f] = *(const bhalf8*)(vT + (bh * 64 + f * 16 + (l & 15)) * 4096 + nb);
    }
    #pragma unroll
    for (int fm = 0; fm < 4; ++fm) {
      #pragma unroll
      for (int fn = 0; fn < 4; ++fn)
        acc[fm][fn] = MFMA16(a[fm], bv[fn], acc[fm][fn]);
      az[fm] = MFMA16(a[fm], ones, az[fm]);   // row-sums -> Z
    }
  }
  #pragma unroll
  for (int fm = 0; fm < 4; ++fm)
    #pragma unroll
    for (int fn = 0; fn < 4; ++fn)
      #pragma unroll
      for (int r = 0; r < 4; ++r) {
        int row = fm * 16 + ((l >> 4) * 4) + r;
        int col = fn * 16 + (l & 15);
        ctx_part[bx * 4096 + row * 64 + col] = acc[fm][fn][r];
      }
  if ((l & 15) == 0) {
    #pragma unroll
    for (int fm = 0; fm < 4; ++fm)
      #pragma unroll
      for (int r = 0; r < 4; ++r)
        z_part[bx * 64 + fm * 16 + ((l >> 4) * 4) + r] = az[fm][r];
  }
}

// ---------------- K4: W2T[b][c][hd] = sum_e (ctx[d][e]/Z[d]) * wp[h*64+e][c]  (bf16 MFMA) ----------------
__global__ __launch_bounds__(256, 1)
void k_w2(const float* __restrict__ ctx_part, const float* __restrict__ z_part,
          const u16* __restrict__ wpT, u16* __restrict__ W2T) {
  const int bh = blockIdx.x;            // 32
  const int b = bh >> 3, h = bh & 7;
  __shared__ float zinv[64];
  __shared__ __align__(16) u16 alds[64][72];
  const int t = threadIdx.x;
  if (t < 64) {
    float zs = 0.f;
    for (int p = 0; p < 16; ++p) zs += z_part[(bh * 16 + p) * 64 + t];
    zinv[t] = 1.0f / zs;
  }
  __syncthreads();
  for (int i = 0; i < 16; ++i) {
    int idx = t * 16 + i;
    int d = idx >> 6, e = idx & 63;
    float s = 0.f;
    for (int p = 0; p < 16; ++p) s += ctx_part[(bh * 16 + p) * 4096 + idx];
    alds[d][e] = f2bf(s * zinv[d]);
  }
  __syncthreads();
  const int w = t >> 6, l = t & 63;
  fx4 acc[4][8];
  const fx4 z4 = {0.f, 0.f, 0.f, 0.f};
  #pragma unroll
  for (int i = 0; i < 4; ++i)
    #pragma unroll
    for (int j = 0; j < 8; ++j) acc[i][j] = z4;
  #pragma unroll
  for (int ks = 0; ks < 2; ++ks) {
    bhalf8 af[4];
    #pragma unroll
    for (int fm = 0; fm < 4; ++fm) {
      int row = fm * 16 + (l & 15);
      af[fm] = *(const bhalf8*)((const char*)alds + row * 144 + ks * 64 + ((l >> 4) * 16));
    }
    #pragma unroll
    for (int fn = 0; fn < 8; ++fn) {
      int c = w * 128 + fn * 16 + (l & 15);
      bhalf8 bv = *(const bhalf8*)(wpT + c * 512 + h * 64 + ks * 32 + ((l >> 4) * 8));
      #pragma unroll
      for (int fm = 0; fm < 4; ++fm)
        acc[fm][fn] = MFMA16(af[fm], bv, acc[fm][fn]);
    }
  }
  #pragma unroll
  for (int fm = 0; fm < 4; ++fm)
    #pragma unroll
    for (int fn = 0; fn < 8; ++fn) {
      int c = w * 128 + fn * 16 + (l & 15);
      int d0 = fm * 16 + ((l >> 4) * 4);
      US4 p;
      #pragma unroll
      for (int r = 0; r < 4; ++r) p.v[r] = f2bf(acc[fm][fn][r]);
      *(US4*)(W2T + (b * 512 + c) * 512 + h * 64 + d0) = p;
    }
}

// ---------------- K5: final GEMM  out = qhat @ W2_b + bias ----------------
__global__ __launch_bounds__(256, 2)
void k_out_gemm(const char* __restrict__ qhat, const char* __restrict__ W2T,
                const float* __restrict__ bproj, float* __restrict__ outp) {
  __shared__ __align__(16) char lds[32768];
  const int bx = blockIdx.x;
  const int tM = bx & 127, tN = bx >> 7;  // 128 M-tiles, 4 N-tiles
  const int b = tM >> 5;
  fx4 acc[4][4];
  const fx4 z4 = {0.f, 0.f, 0.f, 0.f};
  #pragma unroll
  for (int i = 0; i < 4; ++i)
    #pragma unroll
    for (int j = 0; j < 4; ++j) acc[i][j] = z4;

  gemm_core(qhat + tM * 131072, W2T + b * 524288 + tN * 131072, lds, lds + 16384, acc);

  const int t = threadIdx.x, w = t >> 6, l = t & 63;
  const int wm = w >> 1, wn = w & 1;
  const int m0 = tM * 128 + wm * 64;
  const int c0 = tN * 128 + wn * 64;
  #pragma unroll
  for (int fm = 0; fm < 4; ++fm)
    #pragma unroll
    for (int fn = 0; fn < 4; ++fn) {
      int c = c0 + fn * 16 + (l & 15);
      float bp = bproj[c];
      #pragma unroll
      for (int r = 0; r < 4; ++r) {
        int m = m0 + fm * 16 + ((l >> 4) * 4) + r;
        outp[m * 512 + c] = acc[fm][fn][r] + bp;
      }
    }
}

extern "C" void kernel_launch(void* const* d_in, const int* in_sizes, int n_in,
                              void* d_out, int out_size, void* d_ws, size_t ws_size,
                              hipStream_t stream) {
  (void)in_sizes; (void)n_in; (void)out_size;
  const float* x     = (const float*)d_in[0];
  const float* wqkv  = (const float*)d_in[1];
  const float* wproj = (const float*)d_in[2];
  const float* bproj = (const float*)d_in[3];
  float* outp = (float*)d_out;
  char* ws = (char*)d_ws;

  char* xb   = ws;                 // 16384*512*2      = 16,777,216
  char* wqT  = ws + 16777216;      // 1536*512*2       =  1,572,864
  char* wpT  = ws + 18350080;      // 512*512*2        =    524,288
  char* qhat = ws + 18874368;      // 16384*512*2      = 16,777,216
  char* kT   = ws + 35651584;      // 32*64*4096*2     = 16,777,216
  char* vT   = ws + 52428800;      // 16,777,216
  char* ctxp = ws + 69206016;      // 512*4096*4       =  8,388,608
  char* zp   = ws + 77594624;      // 512*64*4         =    131,072
  char* w2t  = ws + 77725696;      // 4*512*512*2      =  2,097,152  (end 79,822,848)
  if (ws_size < 79822848) return;

  k_conv<<<8192, 256, 0, stream>>>(x, (u16*)xb, 2097152);
  k_transpose<<<192, 256, 0, stream>>>(wqkv, (u16*)wqT, 512, 1536, 8);
  k_transpose<<<64, 256, 0, stream>>>(wproj, (u16*)wpT, 512, 512, 8);
  k_qkv_gemm<<<1536, 256, 0, stream>>>(xb, wqT, (u16*)qhat, (u16*)kT, (u16*)vT);
  k_ctx<<<512, 64, 0, stream>>>((const u16*)kT, (const u16*)vT, (float*)ctxp, (float*)zp);
  k_w2<<<32, 256, 0, stream>>>((const float*)ctxp, (const float*)zp, (const u16*)wpT, (u16*)w2t);
  k_out_gemm<<<512, 256, 0, stream>>>(qhat, w2t, bproj, outp);
}

// Round 2
// 83.792 us; speedup vs baseline: 1.2000x; 1.2000x over previous
//
#include <hip/hip_runtime.h>
#include <hip/hip_bf16.h>

typedef unsigned short u16;
typedef __attribute__((ext_vector_type(8))) short bhalf8;
typedef __attribute__((ext_vector_type(4))) float fx4;

struct __align__(8) US4 { u16 v[4]; };

__device__ __forceinline__ u16 f2bf(float x) {
  union { float f; unsigned int u; } c; c.f = x;
  unsigned int r = c.u + 0x7FFFu + ((c.u >> 16) & 1u);
  return (u16)(r >> 16);
}

__device__ __forceinline__ void gload16(const void* g, void* l) {
  __builtin_amdgcn_global_load_lds((const __attribute__((address_space(1))) void*)g,
                                   (__attribute__((address_space(3))) void*)l,
                                   16, 0, 0);
}

#define MFMA16(a, b, c) __builtin_amdgcn_mfma_f32_16x16x32_bf16((a), (b), (c), 0, 0, 0)

// ---------------- input conversion ----------------
__global__ void k_conv(const float* __restrict__ in, u16* __restrict__ out, int n4) {
  int i = blockIdx.x * 256 + threadIdx.x;
  if (i < n4) {
    float4 v = ((const float4*)in)[i];
    US4 o;
    o.v[0] = f2bf(v.x); o.v[1] = f2bf(v.y); o.v[2] = f2bf(v.z); o.v[3] = f2bf(v.w);
    ((US4*)out)[i] = o;
  }
}

// transpose [R][C] f32 -> [C][R] bf16, 64x64 tiles.
// remap!=0: output rows >=512 get per-head K/V interleave:
//   K col c in [512,1024)  -> 512 + h*128 +      (c-512)%64
//   V col c in [1024,1536) -> 512 + h*128 + 64 + (c-1024)%64
__global__ void k_transpose(const float* __restrict__ in, u16* __restrict__ out,
                            int R, int C, int rtiles, int remap) {
  __shared__ float tile[64][65];
  const int bx = blockIdx.x;
  const int rt = bx % rtiles, ct = bx / rtiles;
  const int r0 = rt * 64, c0 = ct * 64;
  const int t = threadIdx.x;
  #pragma unroll
  for (int i = 0; i < 16; ++i) {
    int e = i * 256 + t;
    int rr = e >> 6, cc = e & 63;
    tile[rr][cc] = in[(r0 + rr) * C + c0 + cc];
  }
  __syncthreads();
  #pragma unroll
  for (int i = 0; i < 16; ++i) {
    int e = i * 256 + t;
    int rr = e >> 6, cc = e & 63;
    int orow = c0 + rr;
    if (remap && orow >= 512) {
      int region = (orow - 512) >> 9;       // 0=K, 1=V
      int within = (orow - 512) & 511;
      int h = within >> 6;
      orow = 512 + h * 128 + region * 64 + (within & 63);
    }
    out[orow * R + r0 + cc] = f2bf(tile[cc][rr]);
  }
}

// ---------------- shared 128x128 GEMM mainloop (K=512, both operand row strides = 1024B) ----------------
__device__ __forceinline__ void gemm_core(const char* Ab, const char* Bb,
                                          char* As, char* Bs, fx4 acc[4][4]) {
  const int t = threadIdx.x;
  const int w = t >> 6, l = t & 63;
  const int wm = w >> 1, wn = w & 1;
  #pragma unroll 1
  for (int kt = 0; kt < 8; ++kt) {
    __syncthreads();
    const int kb = kt * 128;
    #pragma unroll
    for (int j = 0; j < 4; ++j) {
      int off = ((j * 4 + w) * 64 + l) * 16;     // byte offset in 16KB tile
      int row = off >> 7;
      int colb = off & 127;
      int scol = colb ^ ((row & 7) << 4);        // pre-swizzled global source
      gload16(Ab + row * 1024 + kb + scol, As + off);
      gload16(Bb + row * 1024 + kb + scol, Bs + off);
    }
    asm volatile("s_waitcnt vmcnt(0)" ::: "memory");
    __syncthreads();
    #pragma unroll
    for (int ks = 0; ks < 2; ++ks) {
      bhalf8 af[4], bfv[4];
      const int kbyte = ks * 64 + ((l >> 4) * 16);
      #pragma unroll
      for (int f = 0; f < 4; ++f) {
        int ra = wm * 64 + f * 16 + (l & 15);
        af[f] = *(const bhalf8*)(As + ra * 128 + (kbyte ^ ((ra & 7) << 4)));
        int rb = wn * 64 + f * 16 + (l & 15);
        bfv[f] = *(const bhalf8*)(Bs + rb * 128 + (kbyte ^ ((rb & 7) << 4)));
      }
      #pragma unroll
      for (int fm = 0; fm < 4; ++fm)
        #pragma unroll
        for (int fn = 0; fn < 4; ++fn)
          acc[fm][fn] = MFMA16(af[fm], bfv[fn], acc[fm][fn]);
    }
  }
}

// ---------------- K1: qkv GEMM + fused q-softmax / k-exp / per-block context partials ----------------
// tN 0..3: Q cols. tN 4..11: head h=tN-4, tile cols 0..63 = K-head-h, 64..127 = V-head-h
__global__ __launch_bounds__(256, 2)
void k_qkv_gemm(const char* __restrict__ xb, const char* __restrict__ wqT,
                u16* __restrict__ qhat, float* __restrict__ ctx_part,
                float* __restrict__ z_part) {
  __shared__ __align__(16) char lds[32768];
  const int bx = blockIdx.x;
  const int tM = bx & 127, tN = bx >> 7;  // 128 M-tiles, 12 N-tiles
  fx4 acc[4][4];
  const fx4 z4 = {0.f, 0.f, 0.f, 0.f};
  #pragma unroll
  for (int i = 0; i < 4; ++i)
    #pragma unroll
    for (int j = 0; j < 4; ++j) acc[i][j] = z4;

  gemm_core(xb + tM * 131072, wqT + tN * 131072, lds, lds + 16384, acc);

  const int t = threadIdx.x, w = t >> 6, l = t & 63;
  const int wm = w >> 1, wn = w & 1;
  const int m0 = tM * 128 + wm * 64;
  const int c0 = tN * 128 + wn * 64;

  if (tN < 4) {
    // q: softmax over the 64 head-dim cols (exactly this wave's col span)
    #pragma unroll
    for (int fm = 0; fm < 4; ++fm) {
      #pragma unroll
      for (int fn = 0; fn < 4; ++fn)
        #pragma unroll
        for (int r = 0; r < 4; ++r)
          acc[fm][fn][r] = __expf(acc[fm][fn][r]);
      fx4 s = acc[fm][0] + acc[fm][1] + acc[fm][2] + acc[fm][3];
      fx4 inv;
      #pragma unroll
      for (int r = 0; r < 4; ++r) {
        float sv = s[r];
        sv += __shfl_xor(sv, 1, 64);
        sv += __shfl_xor(sv, 2, 64);
        sv += __shfl_xor(sv, 4, 64);
        sv += __shfl_xor(sv, 8, 64);
        inv[r] = 1.0f / sv;
      }
      #pragma unroll
      for (int fn = 0; fn < 4; ++fn)
        #pragma unroll
        for (int r = 0; r < 4; ++r) {
          int m = m0 + fm * 16 + ((l >> 4) * 4) + r;
          int c = c0 + fn * 16 + (l & 15);
          qhat[m * 512 + c] = f2bf(acc[fm][fn][r] * inv[r]);
        }
    }
  } else {
    const int h = tN - 4;
    const int b = tM >> 5;
    const int mt = tM & 31;
    const int bh = b * 8 + h;
    char* ktb = lds;            // 64 x 128 bf16, swizzled, 16KB
    char* vtb = lds + 16384;    // 64 x 128 bf16, swizzled, 16KB
    __syncthreads();            // staging LDS free now
    {
      char* dstb = (wn == 0) ? ktb : vtb;
      const bool isK = (wn == 0);
      #pragma unroll
      for (int fm = 0; fm < 4; ++fm)
        #pragma unroll
        for (int fn = 0; fn < 4; ++fn) {
          int d = fn * 16 + (l & 15);
          int n0 = wm * 64 + fm * 16 + ((l >> 4) * 4);
          US4 p;
          #pragma unroll
          for (int r = 0; r < 4; ++r) {
            float v = acc[fm][fn][r];
            if (isK) { float tt = v > 0.f ? v + 1.f : __expf(v); v = __expf(tt); }
            p.v[r] = f2bf(v);
          }
          *(US4*)(dstb + d * 256 + ((2 * n0) ^ ((d & 7) << 4))) = p;
        }
    }
    __syncthreads();
    // ctx[d][e] += sum_n khat[n][d]*v[n][e]; wave w owns d-rows [w*16, w*16+16)
    fx4 cacc[4]; fx4 zacc = z4;
    #pragma unroll
    for (int fn = 0; fn < 4; ++fn) cacc[fn] = z4;
    bhalf8 ones;
    #pragma unroll
    for (int i = 0; i < 8; ++i) ones[i] = (short)0x3F80;  // bf16 1.0
    #pragma unroll
    for (int kk = 0; kk < 4; ++kk) {
      int nbyte = kk * 64 + ((l >> 4) * 16);
      int d = w * 16 + (l & 15);
      bhalf8 a = *(const bhalf8*)(ktb + d * 256 + (nbyte ^ ((d & 7) << 4)));
      #pragma unroll
      for (int fn = 0; fn < 4; ++fn) {
        int e = fn * 16 + (l & 15);
        bhalf8 bv = *(const bhalf8*)(vtb + e * 256 + (nbyte ^ ((e & 7) << 4)));
        cacc[fn] = MFMA16(a, bv, cacc[fn]);
      }
      zacc = MFMA16(a, ones, zacc);
    }
    float* cp = ctx_part + (bh * 32 + mt) * 4096;
    #pragma unroll
    for (int fn = 0; fn < 4; ++fn)
      #pragma unroll
      for (int r = 0; r < 4; ++r) {
        int d = w * 16 + ((l >> 4) * 4) + r;
        int e = fn * 16 + (l & 15);
        cp[d * 64 + e] = cacc[fn][r];
      }
    if ((l & 15) == 0) {
      #pragma unroll
      for (int r = 0; r < 4; ++r)
        z_part[(bh * 32 + mt) * 64 + w * 16 + ((l >> 4) * 4) + r] = zacc[r];
    }
  }
}

// ---------------- K2: reduce ctx partials over the 32 M-blocks ----------------
__global__ __launch_bounds__(256)
void k_reduce(const float* __restrict__ ctx_part, float* __restrict__ ctx32) {
  const int bx = blockIdx.x;    // 512 = 32 bh x 16 slices
  const int bh = bx >> 4;
  const int idx = (bx & 15) * 256 + threadIdx.x;
  float s = 0.f;
  #pragma unroll
  for (int mt = 0; mt < 32; ++mt)
    s += ctx_part[(bh * 32 + mt) * 4096 + idx];
  ctx32[bh * 4096 + idx] = s;
}

// ---------------- K3: W2T[b][c][hd] = sum_e (ctx[d][e]/Z[d]) * wp[h*64+e][c]  (bf16 MFMA) ----------------
__global__ __launch_bounds__(256, 1)
void k_w2(const float* __restrict__ ctx32, const float* __restrict__ z_part,
          const u16* __restrict__ wpT, u16* __restrict__ W2T) {
  const int bh = blockIdx.x;            // 32
  const int b = bh >> 3, h = bh & 7;
  __shared__ float zinv[64];
  __shared__ __align__(16) u16 alds[64][72];
  const int t = threadIdx.x;
  if (t < 64) {
    float zs = 0.f;
    #pragma unroll
    for (int mt = 0; mt < 32; ++mt) zs += z_part[(bh * 32 + mt) * 64 + t];
    zinv[t] = 1.0f / zs;
  }
  __syncthreads();
  #pragma unroll
  for (int i = 0; i < 16; ++i) {
    int idx = i * 256 + t;
    int d = idx >> 6, e = idx & 63;
    alds[d][e] = f2bf(ctx32[bh * 4096 + idx] * zinv[d]);
  }
  __syncthreads();
  const int w = t >> 6, l = t & 63;
  fx4 acc[4][8];
  const fx4 z4 = {0.f, 0.f, 0.f, 0.f};
  #pragma unroll
  for (int i = 0; i < 4; ++i)
    #pragma unroll
    for (int j = 0; j < 8; ++j) acc[i][j] = z4;
  #pragma unroll
  for (int ks = 0; ks < 2; ++ks) {
    bhalf8 af[4];
    #pragma unroll
    for (int fm = 0; fm < 4; ++fm) {
      int row = fm * 16 + (l & 15);
      af[fm] = *(const bhalf8*)((const char*)alds + row * 144 + ks * 64 + ((l >> 4) * 16));
    }
    #pragma unroll
    for (int fn = 0; fn < 8; ++fn) {
      int c = w * 128 + fn * 16 + (l & 15);
      bhalf8 bv = *(const bhalf8*)(wpT + c * 512 + h * 64 + ks * 32 + ((l >> 4) * 8));
      #pragma unroll
      for (int fm = 0; fm < 4; ++fm)
        acc[fm][fn] = MFMA16(af[fm], bv, acc[fm][fn]);
    }
  }
  #pragma unroll
  for (int fm = 0; fm < 4; ++fm)
    #pragma unroll
    for (int fn = 0; fn < 8; ++fn) {
      int c = w * 128 + fn * 16 + (l & 15);
      int d0 = fm * 16 + ((l >> 4) * 4);
      US4 p;
      #pragma unroll
      for (int r = 0; r < 4; ++r) p.v[r] = f2bf(acc[fm][fn][r]);
      *(US4*)(W2T + (b * 512 + c) * 512 + h * 64 + d0) = p;
    }
}

// ---------------- K4: final GEMM  out = qhat @ W2_b + bias ----------------
__global__ __launch_bounds__(256, 2)
void k_out_gemm(const char* __restrict__ qhat, const char* __restrict__ W2T,
                const float* __restrict__ bproj, float* __restrict__ outp) {
  __shared__ __align__(16) char lds[32768];
  const int bx = blockIdx.x;
  const int tM = bx & 127, tN = bx >> 7;  // 128 M-tiles, 4 N-tiles
  const int b = tM >> 5;
  fx4 acc[4][4];
  const fx4 z4 = {0.f, 0.f, 0.f, 0.f};
  #pragma unroll
  for (int i = 0; i < 4; ++i)
    #pragma unroll
    for (int j = 0; j < 4; ++j) acc[i][j] = z4;

  gemm_core(qhat + tM * 131072, W2T + b * 524288 + tN * 131072, lds, lds + 16384, acc);

  const int t = threadIdx.x, w = t >> 6, l = t & 63;
  const int wm = w >> 1, wn = w & 1;
  const int m0 = tM * 128 + wm * 64;
  const int c0 = tN * 128 + wn * 64;
  #pragma unroll
  for (int fm = 0; fm < 4; ++fm)
    #pragma unroll
    for (int fn = 0; fn < 4; ++fn) {
      int c = c0 + fn * 16 + (l & 15);
      float bp = bproj[c];
      #pragma unroll
      for (int r = 0; r < 4; ++r) {
        int m = m0 + fm * 16 + ((l >> 4) * 4) + r;
        outp[m * 512 + c] = acc[fm][fn][r] + bp;
      }
    }
}

extern "C" void kernel_launch(void* const* d_in, const int* in_sizes, int n_in,
                              void* d_out, int out_size, void* d_ws, size_t ws_size,
                              hipStream_t stream) {
  (void)in_sizes; (void)n_in; (void)out_size;
  const float* x     = (const float*)d_in[0];
  const float* wqkv  = (const float*)d_in[1];
  const float* wproj = (const float*)d_in[2];
  const float* bproj = (const float*)d_in[3];
  float* outp = (float*)d_out;
  char* ws = (char*)d_ws;

  char* xb   = ws;                 // 16384*512*2       = 16,777,216
  char* wqT  = ws + 16777216;      // 1536*512*2        =  1,572,864
  char* wpT  = ws + 18350080;      // 512*512*2         =    524,288
  char* qhat = ws + 18874368;      // 16384*512*2       = 16,777,216
  char* ctxp = ws + 35651584;      // 32*32*4096*4      = 16,777,216
  char* zp   = ws + 52428800;      // 32*32*64*4        =    262,144
  char* ctx32= ws + 52690944;      // 32*4096*4         =    524,288
  char* w2t  = ws + 53215232;      // 4*512*512*2       =  2,097,152  (end 55,312,384)
  if (ws_size < 55312384) return;

  k_conv<<<8192, 256, 0, stream>>>(x, (u16*)xb, 2097152);
  k_transpose<<<192, 256, 0, stream>>>(wqkv, (u16*)wqT, 512, 1536, 8, 1);
  k_transpose<<<64, 256, 0, stream>>>(wproj, (u16*)wpT, 512, 512, 8, 0);
  k_qkv_gemm<<<1536, 256, 0, stream>>>(xb, wqT, (u16*)qhat, (float*)ctxp, (float*)zp);
  k_reduce<<<512, 256, 0, stream>>>((const float*)ctxp, (float*)ctx32);
  k_w2<<<32, 256, 0, stream>>>((const float*)ctx32, (const float*)zp, (const u16*)wpT, (u16*)w2t);
  k_out_gemm<<<512, 256, 0, stream>>>(qhat, w2t, bproj, outp);
}